// Round 5
// baseline (292.368 us; speedup 1.0000x reference)
//
#include <hip/hip_runtime.h>

#define B_ 32
#define T_ 512
#define D_ 512
#define MAXF_ 4096
#define FPB_ 64                     // frames per block
#define NBLK_ (B_ * MAXF_ / FPB_)   // 2048 blocks
#define CPB_ (MAXF_ / FPB_)         // 64 chunks per batch

typedef float f4 __attribute__((ext_vector_type(4)));

// Fused length-regulator. vs round 4: FPB 32->64 with 512-thread blocks
// (halves per-CU prologue count: 8 blocks/CU instead of 16) and the store
// loop unroll capped at 8 (caps VGPR so 4 blocks x 512 = 2048 thr/CU stay
// resident -- trade surplus ILP for TLP on the write stream).
__global__ __launch_bounds__(512) void lr_fused_kernel(const f4* __restrict__ x,
                                                       const int* __restrict__ dur,
                                                       f4* __restrict__ out,
                                                       float* __restrict__ mel_out) {
    __shared__ int wsum[8];
    __shared__ int im[FPB_];
    const int tid = threadIdx.x;
    // bijective XCD swizzle: 2048 blocks, 8 XCDs, 256 chunks each
    // (= 4 whole batches per XCD).
    const int bid = ((blockIdx.x & 7) << 8) + (blockIdx.x >> 3);
    const int b  = bid >> 6;                 // 64 chunks per batch
    const int f0 = (bid & 63) * FPB_;        // first frame (batch-local)

    // ---- scan: one duration per thread, shfl wave-scan + 8 wave sums ----
    const int d = dur[b * T_ + tid];
    const int lane = tid & 63;
    const int wave = tid >> 6;
    int v = d;
    #pragma unroll
    for (int off = 1; off < 64; off <<= 1) {
        int u = __shfl_up(v, off, 64);
        if (lane >= off) v += u;
    }
    if (lane == 63) wsum[wave] = v;
    if (tid < FPB_) im[tid] = -1;
    __syncthreads();
    int woff = 0, total = 0;
    #pragma unroll
    for (int w = 0; w < 8; ++w) {            // LDS broadcast, conflict-free
        const int s = wsum[w];
        woff  += (w < wave) ? s : 0;
        total += s;
    }
    const int end = woff + v;                // inclusive prefix for pos tid
    const int start = end - d;

    // ---- scatter coverage clipped to this block's window ----
    const int f1 = f0 + FPB_;
    const int lo = start > f0 ? start : f0;
    const int hi = end < f1 ? end : f1;
    for (int p = lo; p < hi; ++p) im[p - f0] = tid;   // d <= 7 iterations
    if ((bid & 63) == 0 && tid == 0)
        mel_out[b] = (float)(total > 1 ? total : 1);
    __syncthreads();

    // ---- streaming gather: 64 frames, 16 f4 stores/thread, unroll 8 ----
    const f4* __restrict__ xb = x + ((size_t)(b * T_) << 7);
    const int c = tid & 127;                 // f4 column within frame
    const int fbase = tid >> 7;              // 0..3
    const size_t base = (((size_t)b * MAXF_ + f0) << 7) + tid;
    #pragma unroll 8
    for (int k = 0; k < 16; ++k) {
        const int idx = im[fbase + 4 * k];   // wave-uniform LDS broadcast
        const int cidx = idx < 0 ? 0 : idx;  // clamp: masked -> row 0 (hot)
        f4 vv = xb[((size_t)cidx << 7) + c];
        if (idx < 0) vv = (f4){0.f, 0.f, 0.f, 0.f};  // v_cndmask, no branch
        out[base + (size_t)k * 512] = vv;    // plain store (won round-3 A/B)
    }
}

extern "C" void kernel_launch(void* const* d_in, const int* in_sizes, int n_in,
                              void* d_out, int out_size, void* d_ws, size_t ws_size,
                              hipStream_t stream) {
    const float* x = (const float*)d_in[0];
    const int* durations = (const int*)d_in[1];
    float* out = (float*)d_out;
    float* mel_out = out + (size_t)B_ * MAXF_ * D_;
    (void)d_ws; (void)ws_size;

    lr_fused_kernel<<<NBLK_, 512, 0, stream>>>(
        (const f4*)x, durations, (f4*)out, mel_out);
}